// Round 6
// baseline (250.068 us; speedup 1.0000x reference)
//
#include <hip/hip_runtime.h>

typedef float f32x8 __attribute__((ext_vector_type(8)));

#define Bb 256
#define Tt 512
#define Ll 128

// Barrier that waits only on LDS ops (lgkmcnt), NOT in-flight global loads:
// keeps the 4-step-ahead emit/y_true prefetch alive across the barrier.
__device__ __forceinline__ void bar_lgkm() {
  asm volatile("s_waitcnt lgkmcnt(0)" ::: "memory");
  __builtin_amdgcn_s_barrier();
  asm volatile("" ::: "memory");
}

// DPP row_newbcast:Q (gfx90a+/gfx950, ctrl 0x150+Q): every lane of a 16-lane
// row reads lane Q of that row. In-register broadcast on the VALU pipe --
// this removes the 64KB/step LDS broadcast wall of rounds 1-5.
#define BCAST(v, Q) \
  __int_as_float(__builtin_amdgcn_update_dpp( \
      0, __float_as_int(v), 0x150 + (Q), 0xF, 0xF, true))

// 512 threads = 8 waves. Wave w owns states j = 16w + (l&15); row r = l>>4
// handles K-quarter [32r, 32r+32). Lane (r,c) loads u[32r + 4(c&7) .. +3]
// (one ds_read_b128); the 32 MACs for the quarter pull u via row_newbcast
// from lanes 0..7 of the row. Zero compute duplication (512 lanes x 32 MAC
// = 128x128 exactly). Quarter-combine: shfl_xor(16) + shfl_xor(32).
// E slice = 32 floats/lane in 4 named f32x8 SSA values (register-resident,
// proven round 5). Deferred normalization by pivot p = u_prev[0]; C += log p.
__global__ __attribute__((amdgpu_flat_work_group_size(512, 512),
                          amdgpu_waves_per_eu(2, 2)))
void crf_fused(
    const float* __restrict__ yt_g,   // y_true  (B,T,L) one-hot f32
    const float* __restrict__ yp_g,   // y_pred  (B,T,L) f32
    const float* __restrict__ tr_g,   // trans   (L,L)   f32
    float* __restrict__ out)          // (B,1)
{
  __shared__ __align__(32) float u_s[2][Ll];   // exp-domain alpha, double-buffered
  __shared__ int   lab_s[Tt];
  __shared__ float red_s[8][3];

  const int b   = blockIdx.x;
  const int tid = threadIdx.x;        // 0..511
  const int w   = tid >> 6;           // wave 0..7
  const int l   = tid & 63;
  const int j   = (w << 4) | (l & 15);   // state owned: 16 per wave, 128 total
  const int iq  = l >> 4;                // K-quarter / row 0..3
  const int uoff = (iq << 5) | ((l & 7) << 2);  // this lane's u-slice addr

  const float* yp_b = yp_g + (size_t)b * Tt * Ll + j;
  const float* yt_b = yt_g + (size_t)b * Tt * Ll + j;

  // ---- E slice in registers: Es{s}[q] = exp(trans[32*iq + 4q + s][j]) ----
  f32x8 Ea, Eb, Ec, Ed;
  {
    const float* trp = tr_g + (size_t)(iq << 5) * Ll + j;
#define LDE(Q) \
    Ea[Q] = __expf(trp[(4 * (Q) + 0) * Ll]); \
    Eb[Q] = __expf(trp[(4 * (Q) + 1) * Ll]); \
    Ec[Q] = __expf(trp[(4 * (Q) + 2) * Ll]); \
    Ed[Q] = __expf(trp[(4 * (Q) + 3) * Ll]);
    LDE(0) LDE(1) LDE(2) LDE(3) LDE(4) LDE(5) LDE(6) LDE(7)
#undef LDE
  }

  // ---- t = 0 init: v0 = exp(emit0); invariants:
  //   v_t[j] = exp(alpha_t[j] - alpha_{t-1}[0]);  C = sum over steps of log(v[0])
  float pt_acc = 0.f, C = 0.f, un = 0.f;
  {
    float e0 = yp_b[0], y0 = yt_b[0];
    un = __expf(e0);
    if (iq == 0) {
      u_s[0][j] = un;
      pt_acc = e0 * y0;
      if (y0 > 0.5f) lab_s[0] = j;
    }
  }
  // 4-step-lookahead emit/y_true prefetch (step time ~380cyc < HBM ~900cyc,
  // so 2-step lookahead would stall on vmcnt; 4 covers it)
  float pe0 = yp_b[(size_t)1 * Ll], py0 = yt_b[(size_t)1 * Ll];
  float pe1 = yp_b[(size_t)2 * Ll], py1 = yt_b[(size_t)2 * Ll];
  float pe2 = yp_b[(size_t)3 * Ll], py2 = yt_b[(size_t)3 * Ll];
  float pe3 = yp_b[(size_t)4 * Ll], py3 = yt_b[(size_t)4 * Ll];
  bar_lgkm();

#define MAC(Q)                                          \
    acc0 = fmaf(BCAST(u4.x, Q), Ea[Q], acc0);           \
    acc1 = fmaf(BCAST(u4.y, Q), Eb[Q], acc1);           \
    acc2 = fmaf(BCAST(u4.z, Q), Ec[Q], acc2);           \
    acc3 = fmaf(BCAST(u4.w, Q), Ed[Q], acc3);

#define CRF_STEP(T_, PE_, PY_, TN_)                                        \
  {                                                                        \
    const float* usrc = u_s[((T_) + 1) & 1];                               \
    float p = usrc[0];                          /* pivot (broadcast) */    \
    float4 u4 = *(const float4*)(usrc + uoff);  /* lane's u-slice */       \
    float wc = __expf(PE_) * __builtin_amdgcn_rcpf(p); /* off u-chain */   \
    float acc0 = 0.f, acc1 = 0.f, acc2 = 0.f, acc3 = 0.f;                  \
    MAC(0) MAC(1) MAC(2) MAC(3) MAC(4) MAC(5) MAC(6) MAC(7)                \
    float s = (acc0 + acc1) + (acc2 + acc3);                               \
    s += __shfl_xor(s, 16);                     /* combine quarters */     \
    s += __shfl_xor(s, 32);                                                \
    un = s * wc;                                                           \
    if (iq == 0) {                                                         \
      u_s[(T_) & 1][j] = un;                                               \
      pt_acc += PE_ * PY_;                                                 \
      if (PY_ > 0.5f) lab_s[(T_)] = j;                                     \
    }                                                                      \
    C += __logf(p);                             /* off-chain */            \
    {                                                                      \
      int tn = (TN_) < Tt ? (TN_) : (Tt - 1);                              \
      PE_ = yp_b[(size_t)tn * Ll];                                         \
      PY_ = yt_b[(size_t)tn * Ll];                                         \
    }                                                                      \
    bar_lgkm();                                                            \
  }

  // steps 1..508 as x4-unrolled quads, then explicit tail 509,510,511
  for (int t = 1; t + 3 <= Tt - 4; t += 4) {
    CRF_STEP(t,     pe0, py0, t + 4)
    CRF_STEP(t + 1, pe1, py1, t + 5)
    CRF_STEP(t + 2, pe2, py2, t + 6)
    CRF_STEP(t + 3, pe3, py3, t + 7)
  }
  CRF_STEP(Tt - 3, pe0, py0, Tt - 1)
  CRF_STEP(Tt - 2, pe1, py1, Tt - 1)
  CRF_STEP(Tt - 1, pe2, py2, Tt - 1)
#undef CRF_STEP
#undef MAC

  // ---- trans score from labels ----
  float tr_acc = 0.f;
  if (tid < Tt - 1)
    tr_acc = tr_g[lab_s[tid] * Ll + lab_s[tid + 1]];

  // ---- reductions: gate usum/psum by iq==0 so each j counts once ----
  float usum = (iq == 0) ? un : 0.f;
  float psum = pt_acc;     // only iq==0 lanes contributed
  float tsum = tr_acc;
  #pragma unroll
  for (int off = 32; off; off >>= 1) {
    usum += __shfl_xor(usum, off);
    psum += __shfl_xor(psum, off);
    tsum += __shfl_xor(tsum, off);
  }
  if (l == 0) { red_s[w][0] = usum; red_s[w][1] = psum; red_s[w][2] = tsum; }
  bar_lgkm();
  if (tid == 0) {
    float ut = 0.f, pt = 0.f, tt2 = 0.f;
    #pragma unroll
    for (int k = 0; k < 8; ++k) {
      ut  += red_s[k][0];
      pt  += red_s[k][1];
      tt2 += red_s[k][2];
    }
    out[b] = C + __logf(ut) - pt - tt2;
  }
}

extern "C" void kernel_launch(void* const* d_in, const int* in_sizes, int n_in,
                              void* d_out, int out_size, void* d_ws, size_t ws_size,
                              hipStream_t stream) {
  const float* y_true = (const float*)d_in[0];
  const float* y_pred = (const float*)d_in[1];
  const float* trans  = (const float*)d_in[2];
  float* out = (float*)d_out;
  crf_fused<<<dim3(Bb), dim3(512), 0, stream>>>(y_true, y_pred, trans, out);
}

// Round 7
// 179.490 us; speedup vs baseline: 1.3932x; 1.3932x over previous
//
#include <hip/hip_runtime.h>

typedef float f32x8 __attribute__((ext_vector_type(8)));

#define Bb 256
#define Tt 512
#define Ll 128
#define USTRIDE 12   // dwords per 8-float u-chunk: 16 chunks alias banks only 2-way (free)

// Barrier that waits only on LDS ops (lgkmcnt), NOT in-flight global loads:
// keeps the 4-step-ahead emit/y_true prefetch alive across the barrier.
__device__ __forceinline__ void bar_lgkm() {
  asm volatile("s_waitcnt lgkmcnt(0)" ::: "memory");
  __builtin_amdgcn_s_barrier();
  asm volatile("" ::: "memory");
}

// quad_perm DPP reduce-adds (VALU): x + x[lane^1], x + x[lane^2]
__device__ __forceinline__ float dpp_add_xor1(float x) {
  int t = __builtin_amdgcn_update_dpp(0, __float_as_int(x), 0xB1, 0xF, 0xF, true);
  return x + __int_as_float(t);
}
__device__ __forceinline__ float dpp_add_xor2(float x) {
  int t = __builtin_amdgcn_update_dpp(0, __float_as_int(x), 0x4E, 0xF, 0xF, true);
  return x + __int_as_float(t);
}
// gfx950 permlane swaps (VALU, not LDS pipe). After the swap, {a,b} holds
// {s[l], s[l^16]} (resp. ^32) in some order on every lane -> a+b is the
// xor-reduced sum regardless of the instruction's swap convention.
__device__ __forceinline__ float pl16_sum(float s) {
  float a = s, b = s;
  asm("v_permlane16_swap_b32 %0, %1" : "+v"(a), "+v"(b));
  return a + b;
}
__device__ __forceinline__ float pl32_sum(float s) {
  float a = s, b = s;
  asm("v_permlane32_swap_b32 %0, %1" : "+v"(a), "+v"(b));
  return a + b;
}

// 512 threads = 8 waves. Lane (w,l): owns 4 states {16w + (l&12) + m} over
// k-chunk c = (l&3) | ((l>>4)&3)<<2, span [8c, 8c+8). Combine bits are the
// cheap ones: xor1/xor2 via quad_perm DPP, xor16/xor32 via permlane swaps --
// zero LDS-pipe cross-lane ops. Per step per wave: 2 ds_read_b128 (u chunk)
// + 1 b32 pivot + 1 b32 write = ~37 LDS-pipe cycles (vs round 5's ~770/CU).
// E slice = 32 floats/lane in 4 named f32x8 SSA regs. Deferred normalization
// by pivot p = u_prev[0]; C accumulates log p (absmax 0.0 in rounds 3-6).
__global__ __attribute__((amdgpu_flat_work_group_size(512, 512),
                          amdgpu_waves_per_eu(2, 2)))
void crf_fused(
    const float* __restrict__ yt_g,   // y_true  (B,T,L) one-hot f32
    const float* __restrict__ yp_g,   // y_pred  (B,T,L) f32
    const float* __restrict__ tr_g,   // trans   (L,L)   f32
    float* __restrict__ out)          // (B,1)
{
  __shared__ __align__(16) float u_s[2][16 * USTRIDE];  // chunk-strided alpha
  __shared__ int   lab_s[Tt];
  __shared__ float red_s[8][3];

  const int b   = blockIdx.x;
  const int tid = threadIdx.x;        // 0..511
  const int w   = tid >> 6;           // wave 0..7
  const int l   = tid & 63;
  const int j   = (w << 4) | (l & 15);            // emit-state of this lane
  const int jb  = (w << 4) | (l & 12);            // base of its 4-state group
  const int c   = (l & 3) | (((l >> 4) & 3) << 2);// k-chunk 0..15
  const int uoff = c * USTRIDE;                   // chunk dword offset
  const int wdw  = (j >> 3) * USTRIDE + (j & 7);  // writer's dword for state j
  const bool wr  = (l < 16);                      // one writer per state
  const bool b0  = (l & 1), b1 = (l & 2);

  const float* yp_b = yp_g + (size_t)b * Tt * Ll + j;
  const float* yt_b = yt_g + (size_t)b * Tt * Ll + j;

  // ---- E slice in registers: Em[q] = exp(trans[8c+q][jb+m]) ----
  f32x8 E0, E1, E2, E3;
  {
    const float* trp = tr_g + (size_t)(c * 8) * Ll + jb;
    #pragma unroll
    for (int q = 0; q < 8; ++q) {
      E0[q] = __expf(trp[q * Ll + 0]);
      E1[q] = __expf(trp[q * Ll + 1]);
      E2[q] = __expf(trp[q * Ll + 2]);
      E3[q] = __expf(trp[q * Ll + 3]);
    }
  }

  // ---- t = 0 init: v0 = exp(emit0); invariants:
  //   v_t[j] = exp(alpha_t[j] - alpha_{t-1}[0]);  C = sum over steps of log(v[0])
  float pt_acc = 0.f, C = 0.f, un = 0.f;
  {
    float e0 = yp_b[0], y0 = yt_b[0];
    un = __expf(e0);
    pt_acc = e0 * y0;                  // identical across the 4 replicas; gated at end
    if (wr) {
      u_s[0][wdw] = un;
      if (y0 > 0.5f) lab_s[0] = j;
    }
  }
  // 4-step-lookahead emit/y_true prefetch
  float pe0 = yp_b[(size_t)1 * Ll], py0 = yt_b[(size_t)1 * Ll];
  float pe1 = yp_b[(size_t)2 * Ll], py1 = yt_b[(size_t)2 * Ll];
  float pe2 = yp_b[(size_t)3 * Ll], py2 = yt_b[(size_t)3 * Ll];
  float pe3 = yp_b[(size_t)4 * Ll], py3 = yt_b[(size_t)4 * Ll];
  bar_lgkm();

#define CRF_STEP(T_, PE_, PY_, TN_)                                          \
  {                                                                          \
    const float* usrc = u_s[((T_) + 1) & 1];                                 \
    float p = usrc[0];                            /* pivot (broadcast) */    \
    float4 ua = *(const float4*)(usrc + uoff);    /* u[8c .. 8c+3] */        \
    float4 ub = *(const float4*)(usrc + uoff + 4);/* u[8c+4 .. 8c+7] */      \
    float wc = __expf(PE_) * __builtin_amdgcn_rcpf(p);  /* off u-chain */    \
    float a0 = ua.x * E0[0], a1 = ua.x * E1[0];                              \
    float a2 = ua.x * E2[0], a3 = ua.x * E3[0];                              \
    a0 = fmaf(ua.y, E0[1], a0); a1 = fmaf(ua.y, E1[1], a1);                  \
    a2 = fmaf(ua.y, E2[1], a2); a3 = fmaf(ua.y, E3[1], a3);                  \
    a0 = fmaf(ua.z, E0[2], a0); a1 = fmaf(ua.z, E1[2], a1);                  \
    a2 = fmaf(ua.z, E2[2], a2); a3 = fmaf(ua.z, E3[2], a3);                  \
    a0 = fmaf(ua.w, E0[3], a0); a1 = fmaf(ua.w, E1[3], a1);                  \
    a2 = fmaf(ua.w, E2[3], a2); a3 = fmaf(ua.w, E3[3], a3);                  \
    a0 = fmaf(ub.x, E0[4], a0); a1 = fmaf(ub.x, E1[4], a1);                  \
    a2 = fmaf(ub.x, E2[4], a2); a3 = fmaf(ub.x, E3[4], a3);                  \
    a0 = fmaf(ub.y, E0[5], a0); a1 = fmaf(ub.y, E1[5], a1);                  \
    a2 = fmaf(ub.y, E2[5], a2); a3 = fmaf(ub.y, E3[5], a3);                  \
    a0 = fmaf(ub.z, E0[6], a0); a1 = fmaf(ub.z, E1[6], a1);                  \
    a2 = fmaf(ub.z, E2[6], a2); a3 = fmaf(ub.z, E3[6], a3);                  \
    a0 = fmaf(ub.w, E0[7], a0); a1 = fmaf(ub.w, E1[7], a1);                  \
    a2 = fmaf(ub.w, E2[7], a2); a3 = fmaf(ub.w, E3[7], a3);                  \
    a0 = dpp_add_xor1(a0); a1 = dpp_add_xor1(a1);                            \
    a2 = dpp_add_xor1(a2); a3 = dpp_add_xor1(a3);                            \
    a0 = dpp_add_xor2(a0); a1 = dpp_add_xor2(a1);                            \
    a2 = dpp_add_xor2(a2); a3 = dpp_add_xor2(a3);                            \
    float s01 = b0 ? a1 : a0;                     /* keep m = l&3 */         \
    float s23 = b0 ? a3 : a2;                                                \
    float sq  = b1 ? s23 : s01;                                              \
    sq = pl16_sum(sq);                            /* + lane^16 (VALU) */     \
    sq = pl32_sum(sq);                            /* + lane^32 (VALU) */     \
    un = sq * wc;                                                            \
    if (wr) {                                                                \
      u_s[(T_) & 1][wdw] = un;                                               \
      if (PY_ > 0.5f) lab_s[(T_)] = j;                                       \
    }                                                                        \
    pt_acc += PE_ * PY_;                                                     \
    C += __logf(p);                               /* off-chain */            \
    {                                                                        \
      int tn = (TN_) < Tt ? (TN_) : (Tt - 1);                                \
      PE_ = yp_b[(size_t)tn * Ll];                                           \
      PY_ = yt_b[(size_t)tn * Ll];                                           \
    }                                                                        \
    bar_lgkm();                                                              \
  }

  // steps 1..508 as x4-unrolled quads, then explicit tail 509,510,511
  for (int t = 1; t + 3 <= Tt - 4; t += 4) {
    CRF_STEP(t,     pe0, py0, t + 4)
    CRF_STEP(t + 1, pe1, py1, t + 5)
    CRF_STEP(t + 2, pe2, py2, t + 6)
    CRF_STEP(t + 3, pe3, py3, t + 7)
  }
  CRF_STEP(Tt - 3, pe0, py0, Tt - 1)
  CRF_STEP(Tt - 2, pe1, py1, Tt - 1)
  CRF_STEP(Tt - 1, pe2, py2, Tt - 1)
#undef CRF_STEP

  // ---- trans score from labels ----
  float tr_acc = 0.f;
  if (tid < Tt - 1)
    tr_acc = tr_g[lab_s[tid] * Ll + lab_s[tid + 1]];

  // ---- reductions: gate by wr so each state counts once ----
  float usum = wr ? un : 0.f;
  float psum = wr ? pt_acc : 0.f;
  float tsum = tr_acc;
  #pragma unroll
  for (int off = 32; off; off >>= 1) {
    usum += __shfl_xor(usum, off);
    psum += __shfl_xor(psum, off);
    tsum += __shfl_xor(tsum, off);
  }
  if (l == 0) { red_s[w][0] = usum; red_s[w][1] = psum; red_s[w][2] = tsum; }
  bar_lgkm();
  if (tid == 0) {
    float ut = 0.f, pt = 0.f, tt2 = 0.f;
    #pragma unroll
    for (int k = 0; k < 8; ++k) {
      ut  += red_s[k][0];
      pt  += red_s[k][1];
      tt2 += red_s[k][2];
    }
    out[b] = C + __logf(ut) - pt - tt2;
  }
}

extern "C" void kernel_launch(void* const* d_in, const int* in_sizes, int n_in,
                              void* d_out, int out_size, void* d_ws, size_t ws_size,
                              hipStream_t stream) {
  const float* y_true = (const float*)d_in[0];
  const float* y_pred = (const float*)d_in[1];
  const float* trans  = (const float*)d_in[2];
  float* out = (float*)d_out;
  crf_fused<<<dim3(Bb), dim3(512), 0, stream>>>(y_true, y_pred, trans, out);
}

// Round 8
// 164.241 us; speedup vs baseline: 1.5226x; 1.0928x over previous
//
#include <hip/hip_runtime.h>

typedef float f32x8 __attribute__((ext_vector_type(8)));

#define Bb 256
#define Tt 512
#define Ll 128
#define USTRIDE 12   // dwords per 8-float u-chunk: 16 chunks alias banks only 2-way (free)
#define WSTEPS 8
#define NWIN (Tt / WSTEPS)   // 64 windows

// Barrier that waits only on LDS ops (lgkmcnt), NOT in-flight global loads:
// keeps the window-ahead emit/y_true prefetch alive across step barriers.
__device__ __forceinline__ void bar_lgkm() {
  asm volatile("s_waitcnt lgkmcnt(0)" ::: "memory");
  __builtin_amdgcn_s_barrier();
  asm volatile("" ::: "memory");
}

// quad_perm DPP reduce-adds (VALU): x + x[lane^1], x + x[lane^2]
__device__ __forceinline__ float dpp_add_xor1(float x) {
  int t = __builtin_amdgcn_update_dpp(0, __float_as_int(x), 0xB1, 0xF, 0xF, true);
  return x + __int_as_float(t);
}
__device__ __forceinline__ float dpp_add_xor2(float x) {
  int t = __builtin_amdgcn_update_dpp(0, __float_as_int(x), 0x4E, 0xF, 0xF, true);
  return x + __int_as_float(t);
}
// gfx950 permlane swaps (VALU): after swap, {a,b} holds {s[l], s[l^16]}
// (resp ^32) in some order on every lane -> a+b is the xor-reduced sum.
__device__ __forceinline__ float pl16_sum(float s) {
  float a = s, b = s;
  asm("v_permlane16_swap_b32 %0, %1" : "+v"(a), "+v"(b));
  return a + b;
}
__device__ __forceinline__ float pl32_sum(float s) {
  float a = s, b = s;
  asm("v_permlane32_swap_b32 %0, %1" : "+v"(a), "+v"(b));
  return a + b;
}

// 512 threads = 8 waves. Lane (w,l): owns 4 states {16w + (l&12) + m} over
// k-chunk c = (l&3)|(((l>>4)&3)<<2), span [8c,8c+8). Combine: xor1/xor2 via
// quad_perm DPP, select, xor16/xor32 via permlane swaps. Per step per wave:
// 2 ds_read_b128 (u chunk) + (wr) 1 b32 write + barrier. emit/y_true are
// window-batched (8 steps) into registers via 16 scalar loads issued one
// window ahead (vmcnt(0) only at boundaries); exp(emit) hoisted per window;
// point score + one-hot labels processed at boundaries; renorm (pivot
// divide + C += log p) only every 4th step (range-safe: ln u <= ~48 < 88).
__global__ __attribute__((amdgpu_flat_work_group_size(512, 512),
                          amdgpu_waves_per_eu(2, 2)))
void crf_fused(
    const float* __restrict__ yt_g,   // y_true  (B,T,L) one-hot f32
    const float* __restrict__ yp_g,   // y_pred  (B,T,L) f32
    const float* __restrict__ tr_g,   // trans   (L,L)   f32
    float* __restrict__ out)          // (B,1)
{
  __shared__ __align__(16) float u_s[2][16 * USTRIDE];  // chunk-strided alpha
  __shared__ int   lab_s[Tt];
  __shared__ float red_s[8][3];

  const int b   = blockIdx.x;
  const int tid = threadIdx.x;        // 0..511
  const int w   = tid >> 6;           // wave 0..7
  const int l   = tid & 63;
  const int j   = (w << 4) | (l & 15);            // emit-state of this lane
  const int jb  = (w << 4) | (l & 12);            // base of its 4-state group
  const int c   = (l & 3) | (((l >> 4) & 3) << 2);// k-chunk 0..15
  const int uoff = c * USTRIDE;                   // chunk dword offset
  const int wdw  = (j >> 3) * USTRIDE + (j & 7);  // writer's dword for state j
  const bool wr  = (l < 16);                      // one writer per state
  const bool b0  = (l & 1), b1 = (l & 2);

  // ---- E slice in registers: Em[q] = exp(trans[8c+q][jb+m]) ----
  f32x8 E0, E1, E2, E3;
  {
    const float* trp = tr_g + (size_t)(c * 8) * Ll + jb;
    #pragma unroll
    for (int q = 0; q < 8; ++q) {
      E0[q] = __expf(trp[q * Ll + 0]);
      E1[q] = __expf(trp[q * Ll + 1]);
      E2[q] = __expf(trp[q * Ll + 2]);
      E3[q] = __expf(trp[q * Ll + 3]);
    }
  }

  // ---- window staging pointers (column j) ----
  const float* ypw = yp_g + (size_t)b * Tt * Ll + j;   // next window to load
  const float* ytw = yt_g + (size_t)b * Tt * Ll + j;

  float pt_acc = 0.f, C = 0.f, un = 0.f;
  f32x8 pe, py, wex;

  // ---- stage window 0 (blocking) ----
  #pragma unroll
  for (int i = 0; i < 8; ++i) { pe[i] = ypw[i * Ll]; py[i] = ytw[i * Ll]; }
  ypw += WSTEPS * Ll; ytw += WSTEPS * Ll;
  #pragma unroll
  for (int i = 0; i < 8; ++i) wex[i] = __expf(pe[i]);
  #pragma unroll
  for (int i = 0; i < 8; ++i) {
    pt_acc += pe[i] * py[i];
    if (py[i] > 0.5f) lab_s[i] = j;
  }
  // t = 0 init: u0 = exp(emit0)   (invariant: u = exp(alpha)/prod(pivots))
  un = wex[0];
  if (wr) u_s[0][wdw] = un;
  // issue window 1 (consumed at end of win 0)
  #pragma unroll
  for (int i = 0; i < 8; ++i) { pe[i] = ypw[i * Ll]; py[i] = ytw[i * Ll]; }
  ypw += WSTEPS * Ll; ytw += WSTEPS * Ll;
  bar_lgkm();

#define STEP(TOFF, RN)                                                       \
  {                                                                          \
    const float* usrc = &u_s[1 ^ ((TOFF) & 1)][0];                           \
    float4 ua = *(const float4*)(usrc + uoff);                               \
    float4 ub = *(const float4*)(usrc + uoff + 4);                           \
    float p = 0.f, rinv = 0.f;                                               \
    if (RN) { p = usrc[0]; rinv = __builtin_amdgcn_rcpf(p); }                \
    float a0 = ua.x * E0[0], a1 = ua.x * E1[0];                              \
    float a2 = ua.x * E2[0], a3 = ua.x * E3[0];                              \
    a0 = fmaf(ua.y, E0[1], a0); a1 = fmaf(ua.y, E1[1], a1);                  \
    a2 = fmaf(ua.y, E2[1], a2); a3 = fmaf(ua.y, E3[1], a3);                  \
    a0 = fmaf(ua.z, E0[2], a0); a1 = fmaf(ua.z, E1[2], a1);                  \
    a2 = fmaf(ua.z, E2[2], a2); a3 = fmaf(ua.z, E3[2], a3);                  \
    a0 = fmaf(ua.w, E0[3], a0); a1 = fmaf(ua.w, E1[3], a1);                  \
    a2 = fmaf(ua.w, E2[3], a2); a3 = fmaf(ua.w, E3[3], a3);                  \
    a0 = fmaf(ub.x, E0[4], a0); a1 = fmaf(ub.x, E1[4], a1);                  \
    a2 = fmaf(ub.x, E2[4], a2); a3 = fmaf(ub.x, E3[4], a3);                  \
    a0 = fmaf(ub.y, E0[5], a0); a1 = fmaf(ub.y, E1[5], a1);                  \
    a2 = fmaf(ub.y, E2[5], a2); a3 = fmaf(ub.y, E3[5], a3);                  \
    a0 = fmaf(ub.z, E0[6], a0); a1 = fmaf(ub.z, E1[6], a1);                  \
    a2 = fmaf(ub.z, E2[6], a2); a3 = fmaf(ub.z, E3[6], a3);                  \
    a0 = fmaf(ub.w, E0[7], a0); a1 = fmaf(ub.w, E1[7], a1);                  \
    a2 = fmaf(ub.w, E2[7], a2); a3 = fmaf(ub.w, E3[7], a3);                  \
    a0 = dpp_add_xor1(a0); a1 = dpp_add_xor1(a1);                            \
    a2 = dpp_add_xor1(a2); a3 = dpp_add_xor1(a3);                            \
    a0 = dpp_add_xor2(a0); a1 = dpp_add_xor2(a1);                            \
    a2 = dpp_add_xor2(a2); a3 = dpp_add_xor2(a3);                            \
    float s01 = b0 ? a1 : a0;                                                \
    float s23 = b0 ? a3 : a2;                                                \
    float sq  = b1 ? s23 : s01;                                              \
    sq = pl16_sum(sq);                                                       \
    sq = pl32_sum(sq);                                                       \
    float sc = (RN) ? (wex[TOFF] * rinv) : wex[TOFF];                        \
    un = sq * sc;                                                            \
    if (RN) C += __logf(p);                                                  \
    if (wr) u_s[(TOFF) & 1][wdw] = un;                                       \
  }

  for (int win = 0; win < NWIN; ++win) {
    if (win) { STEP(0, 1) bar_lgkm(); }          // t = 8*win (renorm)
    STEP(1, 0) bar_lgkm();
    STEP(2, 0) bar_lgkm();
    STEP(3, 0) bar_lgkm();
    STEP(4, 1) bar_lgkm();                       // renorm
    STEP(5, 0) bar_lgkm();
    STEP(6, 0) bar_lgkm();
    STEP(7, 0)
    if (win + 1 < NWIN) {
      // window boundary: consume win+1 loads, prep wex/pt/labels, issue win+2
      asm volatile("s_waitcnt vmcnt(0)" ::: "memory");
      #pragma unroll
      for (int i = 0; i < 8; ++i) wex[i] = __expf(pe[i]);
      const int wt = (win + 1) * WSTEPS;
      #pragma unroll
      for (int i = 0; i < 8; ++i) {
        pt_acc += pe[i] * py[i];
        if (py[i] > 0.5f) lab_s[wt + i] = j;
      }
      if (win + 2 < NWIN) {
        #pragma unroll
        for (int i = 0; i < 8; ++i) { pe[i] = ypw[i * Ll]; py[i] = ytw[i * Ll]; }
        ypw += WSTEPS * Ll; ytw += WSTEPS * Ll;
      }
    }
    bar_lgkm();
  }
#undef STEP

  // ---- trans score from labels ----
  float tr_acc = 0.f;
  if (tid < Tt - 1)
    tr_acc = tr_g[lab_s[tid] * Ll + lab_s[tid + 1]];

  // ---- reductions: gate by wr so each state counts once ----
  float usum = wr ? un : 0.f;
  float psum = wr ? pt_acc : 0.f;
  float tsum = tr_acc;
  #pragma unroll
  for (int off = 32; off; off >>= 1) {
    usum += __shfl_xor(usum, off);
    psum += __shfl_xor(psum, off);
    tsum += __shfl_xor(tsum, off);
  }
  if (l == 0) { red_s[w][0] = usum; red_s[w][1] = psum; red_s[w][2] = tsum; }
  bar_lgkm();
  if (tid == 0) {
    float ut = 0.f, pt = 0.f, tt2 = 0.f;
    #pragma unroll
    for (int k = 0; k < 8; ++k) {
      ut  += red_s[k][0];
      pt  += red_s[k][1];
      tt2 += red_s[k][2];
    }
    out[b] = C + __logf(ut) - pt - tt2;
  }
}

extern "C" void kernel_launch(void* const* d_in, const int* in_sizes, int n_in,
                              void* d_out, int out_size, void* d_ws, size_t ws_size,
                              hipStream_t stream) {
  const float* y_true = (const float*)d_in[0];
  const float* y_pred = (const float*)d_in[1];
  const float* trans  = (const float*)d_in[2];
  float* out = (float*)d_out;
  crf_fused<<<dim3(Bb), dim3(512), 0, stream>>>(y_true, y_pred, trans, out);
}

// Round 9
// 78.082 us; speedup vs baseline: 3.2026x; 2.1034x over previous
//
#include <hip/hip_runtime.h>

typedef float  f32x4 __attribute__((ext_vector_type(4)));
typedef short  s16x8 __attribute__((ext_vector_type(8)));

#define Tt 512
#define Ll 128

// workspace float offsets
#define WS_PT 0          // [256] point scores (atomicAdd, memset to 0)
#define WS_TR 256        // [256] trans scores (atomicAdd, memset to 0)
#define WS_KR 512        // [256][7] fwd log-scale
#define WS_KB 2304       // [256][7] bwd log-scale
#define WS_RV 4096       // [256][7][128] fwd result vectors (c=0..6)
#define WS_BV 233472     // [256][7][128] bwd result vectors (c=1..7 -> idx c-1)

__device__ __forceinline__ void bar_lgkm() {
  asm volatile("s_waitcnt lgkmcnt(0)" ::: "memory");
  __builtin_amdgcn_s_barrier();
  asm volatile("" ::: "memory");
}
__device__ __forceinline__ ushort bf16rn(float f) {  // RNE f32->bf16 (positive vals)
  unsigned u = __float_as_uint(f);
  u += 0x7FFFu + ((u >> 16) & 1u);
  return (ushort)(u >> 16);
}
__device__ __forceinline__ float bf16tof(ushort h) {
  return __uint_as_float(((unsigned)h) << 16);
}

// 224 blocks = 16 groups x 14 runs. Run 0..6: fwd chunk c=run; run 7..13: bwd
// chunk c=run-6. Each block advances 16 batches' chunk recursion with MFMA:
// per step U(16x128) @ E(128x128) as 4x mfma_f32_16x16x32_bf16 per wave x 8
// waves (j-tiles). E fragments (B operand) live in VGPRs; U round-trips
// through XOR-swizzled bf16 LDS (write D-scaled, read A-frags). K-layout
// errors cancel because A-store and B-fabrication use the same assumed k-map;
// C/D map is the m89-verified col=lane&15,row=4*(lane>>4)+reg.
// fwd: U <- (U@E) o wex_t, t ascending. bwd: V <- E@(wex_t o V) == scale-at-
// store with descending t. Renorm every 8 steps by bf16 pivot u[b][0] with
// exact log bookkeeping. Point score + one-hot labels folded into the loop
// (emissions are loaded anyway); trans pairs from LDS label array.
__global__ __launch_bounds__(512, 1) void crf_chunk(
    const float* __restrict__ yt_g, const float* __restrict__ yp_g,
    const float* __restrict__ tr_g, float* __restrict__ wsf)
{
  __shared__ __align__(16) ushort ubuf[2][16 * 128];  // [buf][batch*128+state] bf16, swizzled
  __shared__ int lab_s[16][65];

  const int bid = blockIdx.x;
  const int g   = bid / 14, run = bid % 14;
  const bool FWD = (run < 7);
  const int c   = FWD ? run : (run - 6);
  const int b0  = g * 16;
  const int tid = threadIdx.x, wv = tid >> 6, l = tid & 63;
  const int l15 = l & 15, q = l >> 4;
  const int jg  = (wv << 4) | l15;          // global state (n-dim of D)
  const int swA = (l15 & 7) << 4;           // A-read row swizzle (row = batch = l15)

  const int t_hi = (c == 7) ? 511 : (c * 64 + 64);
  const int t_lo = c * 64 + 1;
  const int n    = FWD ? 64 : (t_hi - t_lo + 1);   // 64, or 63 for bwd c=7

  // ---- B-operand fragments: Bf[kt][e] = bf16(exp(trans)) at k=32kt+8q+e ----
  s16x8 Bf[4];
  #pragma unroll
  for (int kt = 0; kt < 4; ++kt) {
    s16x8 v;
    #pragma unroll
    for (int e = 0; e < 8; ++e) {
      int k = 32 * kt + 8 * q + e;
      float tv = FWD ? tr_g[k * Ll + l15] : tr_g[l15 * Ll + k];
      v[e] = (short)bf16rn(__expf(tv));
    }
    Bf[kt] = v;
  }

  const size_t ypb0 = ((size_t)(b0 + 4 * q + 0) * Tt) * Ll + jg;
  const size_t ypb1 = ((size_t)(b0 + 4 * q + 1) * Tt) * Ll + jg;
  const size_t ypb2 = ((size_t)(b0 + 4 * q + 2) * Tt) * Ll + jg;
  const size_t ypb3 = ((size_t)(b0 + 4 * q + 3) * Tt) * Ll + jg;

  float pt0 = 0.f, pt1 = 0.f, pt2 = 0.f, pt3 = 0.f;
  float K0 = 0.f, K1 = 0.f, K2 = 0.f, K3 = 0.f;
  float res0 = 0.f, res1 = 0.f, res2 = 0.f, res3 = 0.f;

  // ---- init vector -> buf0 ----
  {
    float iv0, iv1, iv2, iv3;
    if (FWD) {
      if (c == 0) {   // true x0 = exp(emit at t=0); also t=0 point/label
        float e0 = yp_g[ypb0], e1 = yp_g[ypb1], e2 = yp_g[ypb2], e3 = yp_g[ypb3];
        float y0 = yt_g[ypb0], y1 = yt_g[ypb1], y2 = yt_g[ypb2], y3 = yt_g[ypb3];
        iv0 = __expf(e0); iv1 = __expf(e1); iv2 = __expf(e2); iv3 = __expf(e3);
        pt0 = e0 * y0; pt1 = e1 * y1; pt2 = e2 * y2; pt3 = e3 * y3;
        if (y0 > .5f) lab_s[4 * q + 0][0] = jg;
        if (y1 > .5f) lab_s[4 * q + 1][0] = jg;
        if (y2 > .5f) lab_s[4 * q + 2][0] = jg;
        if (y3 > .5f) lab_s[4 * q + 3][0] = jg;
      } else { iv0 = iv1 = iv2 = iv3 = 1.f; }     // ones probe
    } else {          // bwd init: wex[t_hi] o ones
      size_t off = (size_t)t_hi * Ll;
      float e0 = yp_g[ypb0 + off], e1 = yp_g[ypb1 + off],
            e2 = yp_g[ypb2 + off], e3 = yp_g[ypb3 + off];
      iv0 = __expf(e0); iv1 = __expf(e1); iv2 = __expf(e2); iv3 = __expf(e3);
      if (c == 7) {   // t=511 point + label (li = 63)
        float y0 = yt_g[ypb0 + off], y1 = yt_g[ypb1 + off],
              y2 = yt_g[ypb2 + off], y3 = yt_g[ypb3 + off];
        pt0 = e0 * y0; pt1 = e1 * y1; pt2 = e2 * y2; pt3 = e3 * y3;
        if (y0 > .5f) lab_s[4 * q + 0][63] = jg;
        if (y1 > .5f) lab_s[4 * q + 1][63] = jg;
        if (y2 > .5f) lab_s[4 * q + 2][63] = jg;
        if (y3 > .5f) lab_s[4 * q + 3][63] = jg;
      }
    }
    char* wb = (char*)ubuf;   // buf 0
    *(ushort*)(wb + (4*q+0)*256 + ((2*jg) ^ (((4*q+0)&7)<<4))) = bf16rn(iv0);
    *(ushort*)(wb + (4*q+1)*256 + ((2*jg) ^ (((4*q+1)&7)<<4))) = bf16rn(iv1);
    *(ushort*)(wb + (4*q+2)*256 + ((2*jg) ^ (((4*q+2)&7)<<4))) = bf16rn(iv2);
    *(ushort*)(wb + (4*q+3)*256 + ((2*jg) ^ (((4*q+3)&7)<<4))) = bf16rn(iv3);
  }

  // ---- preload emit/y_true slots for k=0,1 (2-deep prefetch) ----
  float PEa0=0,PEa1=0,PEa2=0,PEa3=0, PYa0=0,PYa1=0,PYa2=0,PYa3=0;
  float PEb0=0,PEb1=0,PEb2=0,PEb3=0, PYb0=0,PYb1=0,PYb2=0,PYb3=0;
  {
    int t0s = FWD ? t_lo : (t_hi - 1);
    size_t o = (size_t)t0s * Ll;
    PEa0 = yp_g[ypb0+o]; PEa1 = yp_g[ypb1+o]; PEa2 = yp_g[ypb2+o]; PEa3 = yp_g[ypb3+o];
    if (FWD || c == 7 || 0 >= n - 2) {
      PYa0 = yt_g[ypb0+o]; PYa1 = yt_g[ypb1+o]; PYa2 = yt_g[ypb2+o]; PYa3 = yt_g[ypb3+o];
    }
    int t1s = FWD ? (t_lo + 1) : (t_hi - 2);
    size_t o1 = (size_t)t1s * Ll;
    PEb0 = yp_g[ypb0+o1]; PEb1 = yp_g[ypb1+o1]; PEb2 = yp_g[ypb2+o1]; PEb3 = yp_g[ypb3+o1];
    if (FWD || c == 7 || 1 >= n - 2) {
      PYb0 = yt_g[ypb0+o1]; PYb1 = yt_g[ypb1+o1]; PYb2 = yt_g[ypb2+o1]; PYb3 = yt_g[ypb3+o1];
    }
  }
  bar_lgkm();

#define ITER(K_, PE0,PE1,PE2,PE3, PY0,PY1,PY2,PY3)                            \
  {                                                                           \
    const int cur = (K_) & 1;                                                 \
    const char* abase = (const char*)ubuf + cur * 4096 + l15 * 256;           \
    f32x4 dd = {0.f, 0.f, 0.f, 0.f};                                          \
    _Pragma("unroll")                                                         \
    for (int kt = 0; kt < 4; ++kt) {                                          \
      float4 af = *(const float4*)(abase + ((64 * kt + 16 * q) ^ swA));       \
      dd = __builtin_amdgcn_mfma_f32_16x16x32_bf16(*(const s16x8*)&af,        \
             Bf[kt], dd, 0, 0, 0);                                            \
    }                                                                         \
    const bool last = (K_) == n - 1;                                          \
    const bool ren  = (((K_) & 7) == 7);                                      \
    const int  tsl  = FWD ? (t_lo + (K_)) : (t_hi - (K_) - 1);                \
    const int  li   = tsl - c * 64;                                           \
    const bool doyt = FWD || (c == 7) || (K_) >= n - 2;                       \
    const bool dopt = FWD || ((c == 7) && (K_) <= n - 2);                     \
    float wex0 = __expf(PE0), wex1 = __expf(PE1),                             \
          wex2 = __expf(PE2), wex3 = __expf(PE3);                             \
    if (dopt) { pt0 += PE0*PY0; pt1 += PE1*PY1; pt2 += PE2*PY2; pt3 += PE3*PY3; } \
    if (doyt) {                                                               \
      if (PY0 > .5f) lab_s[4*q+0][li] = jg;                                   \
      if (PY1 > .5f) lab_s[4*q+1][li] = jg;                                   \
      if (PY2 > .5f) lab_s[4*q+2][li] = jg;                                   \
      if (PY3 > .5f) lab_s[4*q+3][li] = jg;                                   \
    }                                                                         \
    float rn0 = 1.f, rn1 = 1.f, rn2 = 1.f, rn3 = 1.f;                         \
    if (ren) {                                                                \
      const char* pb = (const char*)ubuf + cur * 4096;                        \
      float p0 = bf16tof(*(const ushort*)(pb + (4*q+0)*256 + (((4*q+0)&7)<<4))); \
      float p1 = bf16tof(*(const ushort*)(pb + (4*q+1)*256 + (((4*q+1)&7)<<4))); \
      float p2 = bf16tof(*(const ushort*)(pb + (4*q+2)*256 + (((4*q+2)&7)<<4))); \
      float p3 = bf16tof(*(const ushort*)(pb + (4*q+3)*256 + (((4*q+3)&7)<<4))); \
      K0 += __logf(p0); K1 += __logf(p1); K2 += __logf(p2); K3 += __logf(p3); \
      rn0 = 1.f / p0; rn1 = 1.f / p1; rn2 = 1.f / p2; rn3 = 1.f / p3;         \
    }                                                                         \
    float v0 = dd[0], v1 = dd[1], v2 = dd[2], v3 = dd[3];                     \
    if (!(!FWD && last)) { v0 *= wex0; v1 *= wex1; v2 *= wex2; v3 *= wex3; }  \
    if (ren) { v0 *= rn0; v1 *= rn1; v2 *= rn2; v3 *= rn3; }                  \
    if (last) { res0 = v0; res1 = v1; res2 = v2; res3 = v3; }                 \
    else {                                                                    \
      char* wb = (char*)ubuf + (cur ^ 1) * 4096;                              \
      *(ushort*)(wb + (4*q+0)*256 + ((2*jg) ^ (((4*q+0)&7)<<4))) = bf16rn(v0);\
      *(ushort*)(wb + (4*q+1)*256 + ((2*jg) ^ (((4*q+1)&7)<<4))) = bf16rn(v1);\
      *(ushort*)(wb + (4*q+2)*256 + ((2*jg) ^ (((4*q+2)&7)<<4))) = bf16rn(v2);\
      *(ushort*)(wb + (4*q+3)*256 + ((2*jg) ^ (((4*q+3)&7)<<4))) = bf16rn(v3);\
    }                                                                         \
    if ((K_) + 2 < n) {                                                       \
      const int t2 = FWD ? (t_lo + (K_) + 2) : (t_hi - (K_) - 3);             \
      const size_t o2 = (size_t)t2 * Ll;                                      \
      PE0 = yp_g[ypb0+o2]; PE1 = yp_g[ypb1+o2];                               \
      PE2 = yp_g[ypb2+o2]; PE3 = yp_g[ypb3+o2];                               \
      if (FWD || c == 7 || (K_) + 2 >= n - 2) {                               \
        PY0 = yt_g[ypb0+o2]; PY1 = yt_g[ypb1+o2];                             \
        PY2 = yt_g[ypb2+o2]; PY3 = yt_g[ypb3+o2];                             \
      }                                                                       \
    }                                                                         \
    bar_lgkm();                                                               \
  }

  for (int k = 0; k < n; k += 2) {
    ITER(k, PEa0,PEa1,PEa2,PEa3, PYa0,PYa1,PYa2,PYa3)
    if (k + 1 < n) {
      ITER(k + 1, PEb0,PEb1,PEb2,PEb3, PYb0,PYb1,PYb2,PYb3)
    }
  }
#undef ITER

  // ---- store result vectors + K ----
  {
    const int cs = FWD ? c : (c - 1);
    float* rp = wsf + (FWD ? WS_RV : WS_BV);
    rp[((size_t)(b0 + 4*q + 0) * 7 + cs) * 128 + jg] = res0;
    rp[((size_t)(b0 + 4*q + 1) * 7 + cs) * 128 + jg] = res1;
    rp[((size_t)(b0 + 4*q + 2) * 7 + cs) * 128 + jg] = res2;
    rp[((size_t)(b0 + 4*q + 3) * 7 + cs) * 128 + jg] = res3;
    if (wv == 0 && l15 == 0) {
      float* kp = wsf + (FWD ? WS_KR : WS_KB);
      kp[(b0 + 4*q + 0) * 7 + cs] = K0;
      kp[(b0 + 4*q + 1) * 7 + cs] = K1;
      kp[(b0 + 4*q + 2) * 7 + cs] = K2;
      kp[(b0 + 4*q + 3) * 7 + cs] = K3;
    }
  }

  // ---- point-score reduction (over the 16 lanes l15 of each (q,wave)) ----
  {
    float v;
    v = pt0; v += __shfl_xor(v,1); v += __shfl_xor(v,2); v += __shfl_xor(v,4); v += __shfl_xor(v,8);
    if (l15 == 0) atomicAdd(&wsf[WS_PT + b0 + 4*q + 0], v);
    v = pt1; v += __shfl_xor(v,1); v += __shfl_xor(v,2); v += __shfl_xor(v,4); v += __shfl_xor(v,8);
    if (l15 == 0) atomicAdd(&wsf[WS_PT + b0 + 4*q + 1], v);
    v = pt2; v += __shfl_xor(v,1); v += __shfl_xor(v,2); v += __shfl_xor(v,4); v += __shfl_xor(v,8);
    if (l15 == 0) atomicAdd(&wsf[WS_PT + b0 + 4*q + 2], v);
    v = pt3; v += __shfl_xor(v,1); v += __shfl_xor(v,2); v += __shfl_xor(v,4); v += __shfl_xor(v,8);
    if (l15 == 0) atomicAdd(&wsf[WS_PT + b0 + 4*q + 3], v);
  }

  // ---- trans pairs from labels ----
  // fwd c: li = (c==0?0:1)..63; bwd c<7: li=0 only; bwd c==7: li=0..62
  {
    int pbase, npair;
    if (FWD) { pbase = (c == 0) ? 0 : 1; npair = (c == 0) ? 64 : 63; }
    else     { pbase = 0; npair = (c == 7) ? 63 : 1; }
    const int bl = tid >> 5, l32 = tid & 31;
    float trl = 0.f;
    for (int p = pbase + l32; p < pbase + npair; p += 32)
      trl += tr_g[lab_s[bl][p] * Ll + lab_s[bl][p + 1]];
    trl += __shfl_xor(trl, 16); trl += __shfl_xor(trl, 8);
    trl += __shfl_xor(trl, 4);  trl += __shfl_xor(trl, 2);
    trl += __shfl_xor(trl, 1);
    if (l32 == 0) atomicAdd(&wsf[WS_TR + b0 + bl], trl);
  }
}

// logZ = log(r0.b1)+Kr0+Kb1 + sum_{c=1..6}[log(rc.b_{c+1}) + Kb_{c+1} - log(sum rc)]
__global__ __launch_bounds__(64) void crf_stitch(
    const float* __restrict__ wsf, float* __restrict__ out)
{
  const int b = blockIdx.x, j = threadIdx.x;
  const float* RV = wsf + WS_RV + (size_t)b * 7 * 128;
  const float* BV = wsf + WS_BV + (size_t)b * 7 * 128;
  const float* Kr = wsf + WS_KR + b * 7;
  const float* Kb = wsf + WS_KB + b * 7;
  float lz;
  {
    float d = RV[j] * BV[j] + RV[j + 64] * BV[j + 64];
    #pragma unroll
    for (int o = 32; o; o >>= 1) d += __shfl_xor(d, o);
    lz = __logf(d) + Kr[0] + Kb[0];
  }
  #pragma unroll
  for (int cc = 1; cc < 7; ++cc) {
    float d = RV[cc*128 + j] * BV[cc*128 + j] + RV[cc*128 + j + 64] * BV[cc*128 + j + 64];
    float s = RV[cc*128 + j] + RV[cc*128 + j + 64];
    #pragma unroll
    for (int o = 32; o; o >>= 1) { d += __shfl_xor(d, o); s += __shfl_xor(s, o); }
    lz += __logf(d) - __logf(s) + Kb[cc];
  }
  if (j == 0) out[b] = lz - wsf[WS_PT + b] - wsf[WS_TR + b];
}

extern "C" void kernel_launch(void* const* d_in, const int* in_sizes, int n_in,
                              void* d_out, int out_size, void* d_ws, size_t ws_size,
                              hipStream_t stream) {
  const float* y_true = (const float*)d_in[0];
  const float* y_pred = (const float*)d_in[1];
  const float* trans  = (const float*)d_in[2];
  float* out = (float*)d_out;
  float* wsf = (float*)d_ws;
  hipMemsetAsync(d_ws, 0, 2048, stream);   // zero pt/tr accumulators
  crf_chunk<<<dim3(224), dim3(512), 0, stream>>>(y_true, y_pred, trans, wsf);
  crf_stitch<<<dim3(256), dim3(64), 0, stream>>>(wsf, out);
}

// Round 10
// 65.785 us; speedup vs baseline: 3.8013x; 1.1869x over previous
//
#include <hip/hip_runtime.h>

typedef float  f32x4 __attribute__((ext_vector_type(4)));
typedef short  s16x8 __attribute__((ext_vector_type(8)));

#define Tt 512
#define Ll 128
#define CH 16            // chunks
#define CL 32            // steps per chunk
#define NR 15            // probe runs per direction = CH-1
#define RUNS 30          // recursion runs per 16-batch group
#define NSCORE 256       // score blocks (1 per batch)

// workspace float offsets (total ~991k floats ~= 4 MB)
#define WS_PT 0                          // [256] point scores
#define WS_TR 256                        // [256] trans scores
#define WS_KR 512                        // [256][NR] fwd log-scale
#define WS_KB (512 + 256*NR)             // [256][NR] bwd log-scale
#define WS_RV (512 + 2*256*NR)           // [256][NR][128] fwd result vectors
#define WS_BV (WS_RV + 256*NR*128)       // [256][NR][128] bwd result vectors

__device__ __forceinline__ void bar_lgkm() {
  asm volatile("s_waitcnt lgkmcnt(0)" ::: "memory");
  __builtin_amdgcn_s_barrier();
  asm volatile("" ::: "memory");
}
__device__ __forceinline__ ushort bf16rn(float f) {  // RNE f32->bf16 (positive vals)
  unsigned u = __float_as_uint(f);
  u += 0x7FFFu + ((u >> 16) & 1u);
  return (ushort)(u >> 16);
}
__device__ __forceinline__ float bf16tof(ushort h) {
  return __uint_as_float(((unsigned)h) << 16);
}

// Grid = 256 score blocks + 480 recursion blocks (16 groups x 30 runs), all
// co-resident (~3 blocks/CU) so recursion barrier/LDS latency overlaps other
// blocks' compute and score streaming uses the idle HBM bandwidth.
// Score block b: point = sum(y_pred*y_true), one-hot labels -> trans gather.
// Recursion run 0..14: fwd chunk c=run; 15..29: bwd chunk c=run-14.
// Per step U(16x128) @ E(128x128) as 4x mfma_f32_16x16x32_bf16 per wave x 8
// waves; E fragments in VGPRs; U round-trips through XOR-swizzled bf16 LDS.
// Renorm every 8 steps by bf16 pivot with exact log bookkeeping (verified
// round 9, absmax = 1 output ulp).
__global__ __launch_bounds__(512, 1) void crf_chunk(
    const float* __restrict__ yt_g, const float* __restrict__ yp_g,
    const float* __restrict__ tr_g, float* __restrict__ wsf)
{
  __shared__ __align__(16) ushort ubuf[2][16 * 128];  // recursion: U dbuf (bf16, swizzled)
  __shared__ int   lab_s[Tt];                         // score: labels
  __shared__ float redp[8], redt[8];                  // score: reductions

  const int tid = threadIdx.x, wv = tid >> 6, l = tid & 63;

  // ================= score blocks =================
  if (blockIdx.x < NSCORE) {
    const int b = blockIdx.x;
    const float4* yp4 = (const float4*)(yp_g + (size_t)b * Tt * Ll);
    const float4* yt4 = (const float4*)(yt_g + (size_t)b * Tt * Ll);
    float pt = 0.f;
    #pragma unroll 4
    for (int i = 0; i < 32; ++i) {
      int f = tid + i * 512;            // 0..16383 float4s
      float4 a = yp4[f], y = yt4[f];
      pt += a.x * y.x + a.y * y.y + a.z * y.z + a.w * y.w;
      int t = f >> 5, jb = (f & 31) << 2;
      if (y.x > .5f) lab_s[t] = jb;
      if (y.y > .5f) lab_s[t] = jb + 1;
      if (y.z > .5f) lab_s[t] = jb + 2;
      if (y.w > .5f) lab_s[t] = jb + 3;
    }
    __syncthreads();
    float trl = (tid < Tt - 1) ? tr_g[lab_s[tid] * Ll + lab_s[tid + 1]] : 0.f;
    #pragma unroll
    for (int o = 32; o; o >>= 1) { pt += __shfl_xor(pt, o); trl += __shfl_xor(trl, o); }
    if (l == 0) { redp[wv] = pt; redt[wv] = trl; }
    __syncthreads();
    if (tid == 0) {
      float sp = 0.f, st = 0.f;
      #pragma unroll
      for (int k2 = 0; k2 < 8; ++k2) { sp += redp[k2]; st += redt[k2]; }
      wsf[WS_PT + b] = sp; wsf[WS_TR + b] = st;
    }
    return;
  }

  // ================= recursion blocks =================
  const int bid2 = blockIdx.x - NSCORE;
  const int g    = bid2 / RUNS, run = bid2 % RUNS;
  const bool FWD = (run < NR);
  const int c    = FWD ? run : (run - NR + 1);   // fwd c=0..14, bwd c=1..15
  const int b0   = g * 16;
  const int l15  = l & 15, q = l >> 4;
  const int jg   = (wv << 4) | l15;              // global state (n-dim of D)
  const int swA  = (l15 & 7) << 4;               // A-read row swizzle

  const int t_hi = (c == CH - 1) ? (Tt - 1) : (c * CL + CL);
  const int t_lo = c * CL + 1;
  const int n    = FWD ? CL : (t_hi - t_lo + 1); // 32, or 31 for bwd c=15

  // ---- B-operand fragments: Bf[kt][e] = bf16(exp(trans)) at k=32kt+8q+e ----
  s16x8 Bf[4];
  #pragma unroll
  for (int kt = 0; kt < 4; ++kt) {
    s16x8 v;
    #pragma unroll
    for (int e = 0; e < 8; ++e) {
      int k = 32 * kt + 8 * q + e;
      float tv = FWD ? tr_g[k * Ll + l15] : tr_g[l15 * Ll + k];
      v[e] = (short)bf16rn(__expf(tv));
    }
    Bf[kt] = v;
  }

  const size_t ypb0 = ((size_t)(b0 + 4 * q + 0) * Tt) * Ll + jg;
  const size_t ypb1 = ((size_t)(b0 + 4 * q + 1) * Tt) * Ll + jg;
  const size_t ypb2 = ((size_t)(b0 + 4 * q + 2) * Tt) * Ll + jg;
  const size_t ypb3 = ((size_t)(b0 + 4 * q + 3) * Tt) * Ll + jg;

  float K0 = 0.f, K1 = 0.f, K2 = 0.f, K3 = 0.f;
  float res0 = 0.f, res1 = 0.f, res2 = 0.f, res3 = 0.f;

  // ---- init vector -> buf0 ----
  {
    float iv0, iv1, iv2, iv3;
    if (FWD) {
      if (c == 0) {   // true x0 = exp(emit at t=0)
        iv0 = __expf(yp_g[ypb0]); iv1 = __expf(yp_g[ypb1]);
        iv2 = __expf(yp_g[ypb2]); iv3 = __expf(yp_g[ypb3]);
      } else { iv0 = iv1 = iv2 = iv3 = 1.f; }     // ones probe
    } else {          // bwd init: wex[t_hi] o ones
      size_t off = (size_t)t_hi * Ll;
      iv0 = __expf(yp_g[ypb0 + off]); iv1 = __expf(yp_g[ypb1 + off]);
      iv2 = __expf(yp_g[ypb2 + off]); iv3 = __expf(yp_g[ypb3 + off]);
    }
    char* wb = (char*)ubuf;   // buf 0
    *(ushort*)(wb + (4*q+0)*256 + ((2*jg) ^ (((4*q+0)&7)<<4))) = bf16rn(iv0);
    *(ushort*)(wb + (4*q+1)*256 + ((2*jg) ^ (((4*q+1)&7)<<4))) = bf16rn(iv1);
    *(ushort*)(wb + (4*q+2)*256 + ((2*jg) ^ (((4*q+2)&7)<<4))) = bf16rn(iv2);
    *(ushort*)(wb + (4*q+3)*256 + ((2*jg) ^ (((4*q+3)&7)<<4))) = bf16rn(iv3);
  }

  // ---- preload emit slots for k=0,1 (2-deep prefetch) ----
  float PEa0, PEa1, PEa2, PEa3, PEb0, PEb1, PEb2, PEb3;
  {
    size_t o0 = (size_t)(FWD ? t_lo : (t_hi - 1)) * Ll;
    PEa0 = yp_g[ypb0+o0]; PEa1 = yp_g[ypb1+o0]; PEa2 = yp_g[ypb2+o0]; PEa3 = yp_g[ypb3+o0];
    size_t o1 = (size_t)(FWD ? (t_lo + 1) : (t_hi - 2)) * Ll;
    PEb0 = yp_g[ypb0+o1]; PEb1 = yp_g[ypb1+o1]; PEb2 = yp_g[ypb2+o1]; PEb3 = yp_g[ypb3+o1];
  }
  bar_lgkm();

#define ITER(K_, PE0,PE1,PE2,PE3)                                             \
  {                                                                           \
    const int cur = (K_) & 1;                                                 \
    const char* abase = (const char*)ubuf + cur * 4096 + l15 * 256;           \
    f32x4 dd = {0.f, 0.f, 0.f, 0.f};                                          \
    _Pragma("unroll")                                                         \
    for (int kt = 0; kt < 4; ++kt) {                                          \
      float4 af = *(const float4*)(abase + ((64 * kt + 16 * q) ^ swA));       \
      dd = __builtin_amdgcn_mfma_f32_16x16x32_bf16(*(const s16x8*)&af,        \
             Bf[kt], dd, 0, 0, 0);                                            \
    }                                                                         \
    const bool last = (K_) == n - 1;                                          \
    const bool ren  = (((K_) & 7) == 7);                                      \
    float wex0 = __expf(PE0), wex1 = __expf(PE1),                             \
          wex2 = __expf(PE2), wex3 = __expf(PE3);                             \
    float rn0 = 1.f, rn1 = 1.f, rn2 = 1.f, rn3 = 1.f;                         \
    if (ren) {                                                                \
      const char* pb = (const char*)ubuf + cur * 4096;                        \
      float p0 = bf16tof(*(const ushort*)(pb + (4*q+0)*256 + (((4*q+0)&7)<<4))); \
      float p1 = bf16tof(*(const ushort*)(pb + (4*q+1)*256 + (((4*q+1)&7)<<4))); \
      float p2 = bf16tof(*(const ushort*)(pb + (4*q+2)*256 + (((4*q+2)&7)<<4))); \
      float p3 = bf16tof(*(const ushort*)(pb + (4*q+3)*256 + (((4*q+3)&7)<<4))); \
      K0 += __logf(p0); K1 += __logf(p1); K2 += __logf(p2); K3 += __logf(p3); \
      rn0 = 1.f / p0; rn1 = 1.f / p1; rn2 = 1.f / p2; rn3 = 1.f / p3;         \
    }                                                                         \
    float v0 = dd[0], v1 = dd[1], v2 = dd[2], v3 = dd[3];                     \
    if (!(!FWD && last)) { v0 *= wex0; v1 *= wex1; v2 *= wex2; v3 *= wex3; }  \
    if (ren) { v0 *= rn0; v1 *= rn1; v2 *= rn2; v3 *= rn3; }                  \
    if (last) { res0 = v0; res1 = v1; res2 = v2; res3 = v3; }                 \
    else {                                                                    \
      char* wb = (char*)ubuf + (cur ^ 1) * 4096;                              \
      *(ushort*)(wb + (4*q+0)*256 + ((2*jg) ^ (((4*q+0)&7)<<4))) = bf16rn(v0);\
      *(ushort*)(wb + (4*q+1)*256 + ((2*jg) ^ (((4*q+1)&7)<<4))) = bf16rn(v1);\
      *(ushort*)(wb + (4*q+2)*256 + ((2*jg) ^ (((4*q+2)&7)<<4))) = bf16rn(v2);\
      *(ushort*)(wb + (4*q+3)*256 + ((2*jg) ^ (((4*q+3)&7)<<4))) = bf16rn(v3);\
    }                                                                         \
    if ((K_) + 2 < n) {                                                       \
      const size_t o2 = (size_t)(FWD ? (t_lo + (K_) + 2)                      \
                                     : (t_hi - (K_) - 3)) * Ll;               \
      PE0 = yp_g[ypb0+o2]; PE1 = yp_g[ypb1+o2];                               \
      PE2 = yp_g[ypb2+o2]; PE3 = yp_g[ypb3+o2];                               \
    }                                                                         \
    bar_lgkm();                                                               \
  }

  for (int k = 0; k < n; k += 2) {
    ITER(k, PEa0, PEa1, PEa2, PEa3)
    if (k + 1 < n) {
      ITER(k + 1, PEb0, PEb1, PEb2, PEb3)
    }
  }
#undef ITER

  // ---- store result vectors + K ----
  {
    const int cs = FWD ? c : (c - 1);
    float* rp = wsf + (FWD ? WS_RV : WS_BV);
    rp[((size_t)(b0 + 4*q + 0) * NR + cs) * 128 + jg] = res0;
    rp[((size_t)(b0 + 4*q + 1) * NR + cs) * 128 + jg] = res1;
    rp[((size_t)(b0 + 4*q + 2) * NR + cs) * 128 + jg] = res2;
    rp[((size_t)(b0 + 4*q + 3) * NR + cs) * 128 + jg] = res3;
    if (wv == 0 && l15 == 0) {
      float* kp = wsf + (FWD ? WS_KR : WS_KB);
      kp[(b0 + 4*q + 0) * NR + cs] = K0;
      kp[(b0 + 4*q + 1) * NR + cs] = K1;
      kp[(b0 + 4*q + 2) * NR + cs] = K2;
      kp[(b0 + 4*q + 3) * NR + cs] = K3;
    }
  }
}

// logZ = log(r0.b1)+Kr0+Kb1 + sum_{c=1..NR-1}[log(rc.b_{c+1}) + Kb_{c+1} - log(sum rc)]
__global__ __launch_bounds__(64) void crf_stitch(
    const float* __restrict__ wsf, float* __restrict__ out)
{
  const int b = blockIdx.x, j = threadIdx.x;
  const float* RV = wsf + WS_RV + (size_t)b * NR * 128;
  const float* BV = wsf + WS_BV + (size_t)b * NR * 128;
  const float* Kr = wsf + WS_KR + b * NR;
  const float* Kb = wsf + WS_KB + b * NR;
  float lz;
  {
    float d = RV[j] * BV[j] + RV[j + 64] * BV[j + 64];
    #pragma unroll
    for (int o = 32; o; o >>= 1) d += __shfl_xor(d, o);
    lz = __logf(d) + Kr[0] + Kb[0];
  }
  #pragma unroll
  for (int cc = 1; cc < NR; ++cc) {
    float d = RV[cc*128 + j] * BV[cc*128 + j] + RV[cc*128 + j + 64] * BV[cc*128 + j + 64];
    float s = RV[cc*128 + j] + RV[cc*128 + j + 64];
    #pragma unroll
    for (int o = 32; o; o >>= 1) { d += __shfl_xor(d, o); s += __shfl_xor(s, o); }
    lz += __logf(d) - __logf(s) + Kb[cc];
  }
  if (j == 0) out[b] = lz - wsf[WS_PT + b] - wsf[WS_TR + b];
}

extern "C" void kernel_launch(void* const* d_in, const int* in_sizes, int n_in,
                              void* d_out, int out_size, void* d_ws, size_t ws_size,
                              hipStream_t stream) {
  const float* y_true = (const float*)d_in[0];
  const float* y_pred = (const float*)d_in[1];
  const float* trans  = (const float*)d_in[2];
  float* out = (float*)d_out;
  float* wsf = (float*)d_ws;
  crf_chunk<<<dim3(NSCORE + 16 * RUNS), dim3(512), 0, stream>>>(y_true, y_pred, trans, wsf);
  crf_stitch<<<dim3(256), dim3(64), 0, stream>>>(wsf, out);
}

// Round 11
// 63.778 us; speedup vs baseline: 3.9209x; 1.0315x over previous
//
#include <hip/hip_runtime.h>

typedef float  f32x4 __attribute__((ext_vector_type(4)));
typedef short  s16x8 __attribute__((ext_vector_type(8)));

#define Tt 512
#define Ll 128
#define CH 32            // chunks
#define CL 16            // steps per chunk
#define NR 31            // probe runs per direction = CH-1
#define RUNS 62          // recursion runs per 16-batch group
#define NSCORE 256       // score blocks (1 per batch)

// workspace float offsets (total ~2.05M floats ~= 8.2 MB)
#define WS_PT 0                          // [256] point scores
#define WS_TR 256                        // [256] trans scores
#define WS_KR 512                        // [256][NR] fwd log-scale
#define WS_KB (512 + 256*NR)             // [256][NR] bwd log-scale
#define WS_RV (512 + 2*256*NR)           // [256][NR][128] fwd result vectors
#define WS_BV (WS_RV + 256*NR*128)       // [256][NR][128] bwd result vectors

__device__ __forceinline__ void bar_lgkm() {
  asm volatile("s_waitcnt lgkmcnt(0)" ::: "memory");
  __builtin_amdgcn_s_barrier();
  asm volatile("" ::: "memory");
}
__device__ __forceinline__ ushort bf16rn(float f) {  // RNE f32->bf16 (positive vals)
  unsigned u = __float_as_uint(f);
  u += 0x7FFFu + ((u >> 16) & 1u);
  return (ushort)(u >> 16);
}
__device__ __forceinline__ float bf16tof(ushort h) {
  return __uint_as_float(((unsigned)h) << 16);
}

// Grid = 256 score blocks + 992 recursion blocks (16 groups x 62 runs), 256
// threads each (~4 blocks/CU co-resident). Recursion block: 4 waves, wave wv
// owns j-tiles wv (states 16wv..16wv+15) AND wv+4 (+64): each A-frag
// ds_read_b128 feeds TWO independent MFMAs (halves LDS read duplication,
// doubles MFMA ILP). B-frag columns FIXED to the wave's own tile (jg), which
// rounds 9/10 got wrong (used cols 0..15 for every wave; masked by bf16-ulp
// quantization of the output). k-map mismatches still cancel (A-store and
// B-fab share the assumed map); C/D map is m89-verified.
__global__ __attribute__((amdgpu_flat_work_group_size(256, 256),
                          amdgpu_waves_per_eu(2, 4)))
void crf_chunk(
    const float* __restrict__ yt_g, const float* __restrict__ yp_g,
    const float* __restrict__ tr_g, float* __restrict__ wsf)
{
  __shared__ __align__(16) ushort ubuf[2][16 * 128];  // U dbuf (bf16, swizzled)
  __shared__ int   lab_s[Tt];                         // score: labels
  __shared__ float redp[4], redt[4];                  // score: reductions

  const int tid = threadIdx.x, wv = tid >> 6, l = tid & 63;

  // ================= score blocks =================
  if (blockIdx.x < NSCORE) {
    const int b = blockIdx.x;
    const float4* yp4 = (const float4*)(yp_g + (size_t)b * Tt * Ll);
    const float4* yt4 = (const float4*)(yt_g + (size_t)b * Tt * Ll);
    float pt = 0.f;
    #pragma unroll 4
    for (int i = 0; i < 64; ++i) {
      int f = tid + i * 256;            // 0..16383 float4s
      float4 a = yp4[f], y = yt4[f];
      pt += a.x * y.x + a.y * y.y + a.z * y.z + a.w * y.w;
      int t = f >> 5, jb = (f & 31) << 2;
      if (y.x > .5f) lab_s[t] = jb;
      if (y.y > .5f) lab_s[t] = jb + 1;
      if (y.z > .5f) lab_s[t] = jb + 2;
      if (y.w > .5f) lab_s[t] = jb + 3;
    }
    __syncthreads();
    float trl = 0.f;
    for (int tt0 = tid; tt0 < Tt - 1; tt0 += 256)
      trl += tr_g[lab_s[tt0] * Ll + lab_s[tt0 + 1]];
    #pragma unroll
    for (int o = 32; o; o >>= 1) { pt += __shfl_xor(pt, o); trl += __shfl_xor(trl, o); }
    if (l == 0) { redp[wv] = pt; redt[wv] = trl; }
    __syncthreads();
    if (tid == 0) {
      wsf[WS_PT + b] = redp[0] + redp[1] + redp[2] + redp[3];
      wsf[WS_TR + b] = redt[0] + redt[1] + redt[2] + redt[3];
    }
    return;
  }

  // ================= recursion blocks =================
  const int bid2 = blockIdx.x - NSCORE;
  const int g    = bid2 / RUNS, run = bid2 % RUNS;
  const bool FWD = (run < NR);
  const int c    = FWD ? run : (run - NR + 1);   // fwd c=0..30, bwd c=1..31
  const int b0   = g * 16;
  const int l15  = l & 15, q = l >> 4;
  const int jg0  = (wv << 4) | l15;              // tile A state
  const int jg1  = jg0 + 64;                     // tile B state
  const int swA  = (l15 & 7) << 4;               // A-read row swizzle

  const int t_hi = (c == CH - 1) ? (Tt - 1) : (c * CL + CL);
  const int t_lo = c * CL + 1;
  const int n    = FWD ? CL : (t_hi - t_lo + 1); // 16, or 15 for bwd c=31

  // ---- B-operand fragments (column = OWN tile state), k = 32kt+8q+e ----
  s16x8 BfA[4], BfB[4];
  #pragma unroll
  for (int kt = 0; kt < 4; ++kt) {
    s16x8 va, vb;
    #pragma unroll
    for (int e = 0; e < 8; ++e) {
      int k = 32 * kt + 8 * q + e;
      float ta = FWD ? tr_g[k * Ll + jg0] : tr_g[jg0 * Ll + k];
      float tb = FWD ? tr_g[k * Ll + jg1] : tr_g[jg1 * Ll + k];
      va[e] = (short)bf16rn(__expf(ta));
      vb[e] = (short)bf16rn(__expf(tb));
    }
    BfA[kt] = va; BfB[kt] = vb;
  }

  const size_t ypb0 = ((size_t)(b0 + 4 * q + 0) * Tt) * Ll + jg0;
  const size_t ypb1 = ((size_t)(b0 + 4 * q + 1) * Tt) * Ll + jg0;
  const size_t ypb2 = ((size_t)(b0 + 4 * q + 2) * Tt) * Ll + jg0;
  const size_t ypb3 = ((size_t)(b0 + 4 * q + 3) * Tt) * Ll + jg0;

  float K0 = 0.f, K1 = 0.f, K2 = 0.f, K3 = 0.f;
  float rA0 = 0.f, rA1 = 0.f, rA2 = 0.f, rA3 = 0.f;
  float rB0 = 0.f, rB1 = 0.f, rB2 = 0.f, rB3 = 0.f;

#define SWZ(B_) (((B_) & 7) << 4)
#define WRT(BUF, M_, JG, V_) \
  *(ushort*)((char*)ubuf + (BUF) * 4096 + (4*q+(M_))*256 + ((2*(JG)) ^ SWZ(4*q+(M_)))) = bf16rn(V_)

  // ---- init vector -> buf0 ----
  {
    float a0, a1, a2, a3, bb0, bb1, bb2, bb3;
    if (FWD && c != 0) {
      a0 = a1 = a2 = a3 = bb0 = bb1 = bb2 = bb3 = 1.f;   // ones probe
    } else {
      size_t off = FWD ? 0 : (size_t)t_hi * Ll;          // c==0: t=0; bwd: t_hi
      a0  = __expf(yp_g[ypb0 + off]); a1  = __expf(yp_g[ypb1 + off]);
      a2  = __expf(yp_g[ypb2 + off]); a3  = __expf(yp_g[ypb3 + off]);
      bb0 = __expf(yp_g[ypb0 + off + 64]); bb1 = __expf(yp_g[ypb1 + off + 64]);
      bb2 = __expf(yp_g[ypb2 + off + 64]); bb3 = __expf(yp_g[ypb3 + off + 64]);
    }
    WRT(0, 0, jg0, a0); WRT(0, 1, jg0, a1); WRT(0, 2, jg0, a2); WRT(0, 3, jg0, a3);
    WRT(0, 0, jg1, bb0); WRT(0, 1, jg1, bb1); WRT(0, 2, jg1, bb2); WRT(0, 3, jg1, bb3);
  }

  // ---- preload emit slots for k=0,1 (2-deep prefetch) ----
  float EAa0, EAa1, EAa2, EAa3, EBa0, EBa1, EBa2, EBa3;
  float EAb0, EAb1, EAb2, EAb3, EBb0, EBb1, EBb2, EBb3;
  {
    size_t o0 = (size_t)(FWD ? t_lo : (t_hi - 1)) * Ll;
    EAa0 = yp_g[ypb0+o0];    EAa1 = yp_g[ypb1+o0];
    EAa2 = yp_g[ypb2+o0];    EAa3 = yp_g[ypb3+o0];
    EBa0 = yp_g[ypb0+o0+64]; EBa1 = yp_g[ypb1+o0+64];
    EBa2 = yp_g[ypb2+o0+64]; EBa3 = yp_g[ypb3+o0+64];
    size_t o1 = (size_t)(FWD ? (t_lo + 1) : (t_hi - 2)) * Ll;
    EAb0 = yp_g[ypb0+o1];    EAb1 = yp_g[ypb1+o1];
    EAb2 = yp_g[ypb2+o1];    EAb3 = yp_g[ypb3+o1];
    EBb0 = yp_g[ypb0+o1+64]; EBb1 = yp_g[ypb1+o1+64];
    EBb2 = yp_g[ypb2+o1+64]; EBb3 = yp_g[ypb3+o1+64];
  }
  bar_lgkm();

#define ITER(K_, A0,A1,A2,A3, B0,B1,B2,B3)                                    \
  {                                                                           \
    const int cur = (K_) & 1;                                                 \
    const char* abase = (const char*)ubuf + cur * 4096 + l15 * 256;           \
    f32x4 dd0 = {0.f,0.f,0.f,0.f}, dd1 = {0.f,0.f,0.f,0.f};                   \
    _Pragma("unroll")                                                         \
    for (int kt = 0; kt < 4; ++kt) {                                          \
      float4 af = *(const float4*)(abase + ((64 * kt + 16 * q) ^ swA));       \
      dd0 = __builtin_amdgcn_mfma_f32_16x16x32_bf16(*(const s16x8*)&af,       \
              BfA[kt], dd0, 0, 0, 0);                                         \
      dd1 = __builtin_amdgcn_mfma_f32_16x16x32_bf16(*(const s16x8*)&af,       \
              BfB[kt], dd1, 0, 0, 0);                                         \
    }                                                                         \
    const bool last = (K_) == n - 1;                                          \
    const bool ren  = (((K_) & 7) == 7);                                      \
    float wA0 = __expf(A0), wA1 = __expf(A1), wA2 = __expf(A2), wA3 = __expf(A3); \
    float wB0 = __expf(B0), wB1 = __expf(B1), wB2 = __expf(B2), wB3 = __expf(B3); \
    float rn0 = 1.f, rn1 = 1.f, rn2 = 1.f, rn3 = 1.f;                         \
    if (ren) {                                                                \
      const char* pb = (const char*)ubuf + cur * 4096;                        \
      float p0 = bf16tof(*(const ushort*)(pb + (4*q+0)*256 + SWZ(4*q+0)));    \
      float p1 = bf16tof(*(const ushort*)(pb + (4*q+1)*256 + SWZ(4*q+1)));    \
      float p2 = bf16tof(*(const ushort*)(pb + (4*q+2)*256 + SWZ(4*q+2)));    \
      float p3 = bf16tof(*(const ushort*)(pb + (4*q+3)*256 + SWZ(4*q+3)));    \
      K0 += __logf(p0); K1 += __logf(p1); K2 += __logf(p2); K3 += __logf(p3); \
      rn0 = 1.f / p0; rn1 = 1.f / p1; rn2 = 1.f / p2; rn3 = 1.f / p3;         \
    }                                                                         \
    float v0 = dd0[0], v1 = dd0[1], v2 = dd0[2], v3 = dd0[3];                 \
    float u0 = dd1[0], u1 = dd1[1], u2 = dd1[2], u3 = dd1[3];                 \
    if (!(!FWD && last)) {                                                    \
      v0 *= wA0; v1 *= wA1; v2 *= wA2; v3 *= wA3;                             \
      u0 *= wB0; u1 *= wB1; u2 *= wB2; u3 *= wB3;                             \
    }                                                                         \
    if (ren) {                                                                \
      v0 *= rn0; v1 *= rn1; v2 *= rn2; v3 *= rn3;                             \
      u0 *= rn0; u1 *= rn1; u2 *= rn2; u3 *= rn3;                             \
    }                                                                         \
    if (last) {                                                               \
      rA0 = v0; rA1 = v1; rA2 = v2; rA3 = v3;                                 \
      rB0 = u0; rB1 = u1; rB2 = u2; rB3 = u3;                                 \
    } else {                                                                  \
      const int nb = cur ^ 1;                                                 \
      WRT(nb, 0, jg0, v0); WRT(nb, 1, jg0, v1);                               \
      WRT(nb, 2, jg0, v2); WRT(nb, 3, jg0, v3);                               \
      WRT(nb, 0, jg1, u0); WRT(nb, 1, jg1, u1);                               \
      WRT(nb, 2, jg1, u2); WRT(nb, 3, jg1, u3);                               \
    }                                                                         \
    if ((K_) + 2 < n) {                                                       \
      const size_t o2 = (size_t)(FWD ? (t_lo + (K_) + 2)                      \
                                     : (t_hi - (K_) - 3)) * Ll;               \
      A0 = yp_g[ypb0+o2];    A1 = yp_g[ypb1+o2];                              \
      A2 = yp_g[ypb2+o2];    A3 = yp_g[ypb3+o2];                              \
      B0 = yp_g[ypb0+o2+64]; B1 = yp_g[ypb1+o2+64];                           \
      B2 = yp_g[ypb2+o2+64]; B3 = yp_g[ypb3+o2+64];                           \
    }                                                                         \
    bar_lgkm();                                                               \
  }

  for (int k = 0; k < n; k += 2) {
    ITER(k, EAa0,EAa1,EAa2,EAa3, EBa0,EBa1,EBa2,EBa3)
    if (k + 1 < n) {
      ITER(k + 1, EAb0,EAb1,EAb2,EAb3, EBb0,EBb1,EBb2,EBb3)
    }
  }
#undef ITER
#undef WRT
#undef SWZ

  // ---- store result vectors + K ----
  {
    const int cs = FWD ? c : (c - 1);
    float* rp = wsf + (FWD ? WS_RV : WS_BV);
    rp[((size_t)(b0 + 4*q + 0) * NR + cs) * 128 + jg0] = rA0;
    rp[((size_t)(b0 + 4*q + 1) * NR + cs) * 128 + jg0] = rA1;
    rp[((size_t)(b0 + 4*q + 2) * NR + cs) * 128 + jg0] = rA2;
    rp[((size_t)(b0 + 4*q + 3) * NR + cs) * 128 + jg0] = rA3;
    rp[((size_t)(b0 + 4*q + 0) * NR + cs) * 128 + jg1] = rB0;
    rp[((size_t)(b0 + 4*q + 1) * NR + cs) * 128 + jg1] = rB1;
    rp[((size_t)(b0 + 4*q + 2) * NR + cs) * 128 + jg1] = rB2;
    rp[((size_t)(b0 + 4*q + 3) * NR + cs) * 128 + jg1] = rB3;
    if (wv == 0 && l15 == 0) {
      float* kp = wsf + (FWD ? WS_KR : WS_KB);
      kp[(b0 + 4*q + 0) * NR + cs] = K0;
      kp[(b0 + 4*q + 1) * NR + cs] = K1;
      kp[(b0 + 4*q + 2) * NR + cs] = K2;
      kp[(b0 + 4*q + 3) * NR + cs] = K3;
    }
  }
}

// logZ = log(r0.b1)+Kr0+Kb1 + sum_{c=1..NR-1}[log(rc.b_{c+1}) + Kb_{c+1} - log(sum rc)]
__global__ __launch_bounds__(64) void crf_stitch(
    const float* __restrict__ wsf, float* __restrict__ out)
{
  const int b = blockIdx.x, j = threadIdx.x;
  const float* RV = wsf + WS_RV + (size_t)b * NR * 128;
  const float* BV = wsf + WS_BV + (size_t)b * NR * 128;
  const float* Kr = wsf + WS_KR + b * NR;
  const float* Kb = wsf + WS_KB + b * NR;
  float lz;
  {
    float d = RV[j] * BV[j] + RV[j + 64] * BV[j + 64];
    #pragma unroll
    for (int o = 32; o; o >>= 1) d += __shfl_xor(d, o);
    lz = __logf(d) + Kr[0] + Kb[0];
  }
  #pragma unroll
  for (int cc = 1; cc < NR; ++cc) {
    float d = RV[cc*128 + j] * BV[cc*128 + j] + RV[cc*128 + j + 64] * BV[cc*128 + j + 64];
    float s = RV[cc*128 + j] + RV[cc*128 + j + 64];
    #pragma unroll
    for (int o = 32; o; o >>= 1) { d += __shfl_xor(d, o); s += __shfl_xor(s, o); }
    lz += __logf(d) - __logf(s) + Kb[cc];
  }
  if (j == 0) out[b] = lz - wsf[WS_PT + b] - wsf[WS_TR + b];
}

extern "C" void kernel_launch(void* const* d_in, const int* in_sizes, int n_in,
                              void* d_out, int out_size, void* d_ws, size_t ws_size,
                              hipStream_t stream) {
  const float* y_true = (const float*)d_in[0];
  const float* y_pred = (const float*)d_in[1];
  const float* trans  = (const float*)d_in[2];
  float* out = (float*)d_out;
  float* wsf = (float*)d_ws;
  crf_chunk<<<dim3(NSCORE + 16 * RUNS), dim3(256), 0, stream>>>(y_true, y_pred, trans, wsf);
  crf_stitch<<<dim3(256), dim3(64), 0, stream>>>(wsf, out);
}